// Round 1
// baseline (1144.828 us; speedup 1.0000x reference)
//
#include <hip/hip_runtime.h>
#include <hip/hip_bf16.h>
#include <math.h>

#define TOKENS 8192
#define DMODEL 1024
#define DFF    4096
#define NEXP   8
#define PAD_ROWS 17408     // 16384 + 8*128 worst-case padded pair rows
#define MAX_SLOTS 160      // worst case is 136 M-tiles
#define LDSPITCH 40        // bf16 elems per LDS row: 32 + 8 pad (80B stride, 16B aligned)

typedef __bf16 bf16;
typedef bf16  bf16x8 __attribute__((ext_vector_type(8)));
typedef float f32x4  __attribute__((ext_vector_type(4)));

// ---------------- gating: one wave per token ----------------
__global__ __launch_bounds__(256) void gate_kernel(
    const float* __restrict__ x, const float* __restrict__ gw, const float* __restrict__ gb,
    int* __restrict__ counts, int2* __restrict__ topk_i, float2* __restrict__ topk_p)
{
    int wid  = (blockIdx.x * blockDim.x + threadIdx.x) >> 6;   // token id
    int lane = threadIdx.x & 63;
    if (wid >= TOKENS) return;
    const float* xr = x + (size_t)wid * DMODEL;
    float a0=0,a1=0,a2=0,a3=0,a4=0,a5=0,a6=0,a7=0;
    #pragma unroll
    for (int i = 0; i < DMODEL/64; ++i) {
        int d = lane + (i << 6);
        float xv = xr[d];
        const float4* g = (const float4*)(gw + (size_t)d * NEXP);
        float4 g0 = g[0], g1 = g[1];
        a0 += xv * g0.x; a1 += xv * g0.y; a2 += xv * g0.z; a3 += xv * g0.w;
        a4 += xv * g1.x; a5 += xv * g1.y; a6 += xv * g1.z; a7 += xv * g1.w;
    }
    #pragma unroll
    for (int off = 32; off; off >>= 1) {
        a0 += __shfl_xor(a0, off); a1 += __shfl_xor(a1, off);
        a2 += __shfl_xor(a2, off); a3 += __shfl_xor(a3, off);
        a4 += __shfl_xor(a4, off); a5 += __shfl_xor(a5, off);
        a6 += __shfl_xor(a6, off); a7 += __shfl_xor(a7, off);
    }
    float l[NEXP] = { a0+gb[0], a1+gb[1], a2+gb[2], a3+gb[3],
                      a4+gb[4], a5+gb[5], a6+gb[6], a7+gb[7] };
    float m = l[0];
    #pragma unroll
    for (int e = 1; e < NEXP; ++e) m = fmaxf(m, l[e]);
    float p[NEXP], s = 0.f;
    #pragma unroll
    for (int e = 0; e < NEXP; ++e) { p[e] = expf(l[e] - m); s += p[e]; }
    float inv = 1.0f / s;
    int i1 = 0; float b1v = p[0];
    #pragma unroll
    for (int e = 1; e < NEXP; ++e) if (p[e] > b1v) { b1v = p[e]; i1 = e; }
    int i2 = -1; float b2v = -1.f;
    #pragma unroll
    for (int e = 0; e < NEXP; ++e) if (e != i1 && p[e] > b2v) { b2v = p[e]; i2 = e; }
    if (lane == 0) {
        topk_i[wid] = make_int2(i1, i2);
        topk_p[wid] = make_float2(b1v * inv, b2v * inv);
        atomicAdd(&counts[i1], 1);
        atomicAdd(&counts[i2], 1);
    }
}

// ---------------- routing tables (trivial single-thread) ----------------
__global__ void build_slots(const int* __restrict__ counts, int* seg_base, int* n_slots,
                            int* slot_e, int* slot_row0, int* slot_gbase)
{
    if (threadIdx.x == 0 && blockIdx.x == 0) {
        int base = 0, s = 0;
        for (int e = 0; e < NEXP; ++e) {
            int c = counts[e];
            seg_base[e] = base;
            int nt = (c + 127) >> 7;
            for (int i = 0; i < nt; ++i) {
                slot_e[s] = e; slot_row0[s] = i << 7; slot_gbase[s] = base; ++s;
            }
            base += nt << 7;
        }
        *n_slots = s;
    }
}

__global__ __launch_bounds__(256) void scatter_kernel(
    const int2* __restrict__ topk_i, const float2* __restrict__ topk_p,
    const int* __restrict__ seg_base, int* __restrict__ cursor,
    int* __restrict__ token_ids, float* __restrict__ pair_p)
{
    int t = blockIdx.x * 256 + threadIdx.x;
    if (t >= TOKENS) return;
    int2 ki = topk_i[t]; float2 kp = topk_p[t];
    int p0 = seg_base[ki.x] + atomicAdd(&cursor[ki.x], 1);
    token_ids[p0] = t; pair_p[p0] = kp.x;
    int p1 = seg_base[ki.y] + atomicAdd(&cursor[ki.y], 1);
    token_ids[p1] = t; pair_p[p1] = kp.y;
}

// ---------------- fp32 [E][R][C] -> bf16 [E][C][R] ----------------
__global__ __launch_bounds__(256) void transpose_cvt(
    const float* __restrict__ src, bf16* __restrict__ dst, int R, int C)
{
    __shared__ float tile[32][33];
    int e = blockIdx.z;
    int c0 = blockIdx.x * 32, r0 = blockIdx.y * 32;
    const float* s = src + (size_t)e * R * C;
    bf16* d = dst + (size_t)e * R * C;
    int tx = threadIdx.x, ty = threadIdx.y;
    #pragma unroll
    for (int i = 0; i < 4; ++i)
        tile[ty + 8*i][tx] = s[(size_t)(r0 + ty + 8*i) * C + c0 + tx];
    __syncthreads();
    #pragma unroll
    for (int i = 0; i < 4; ++i)
        d[(size_t)(c0 + ty + 8*i) * R + r0 + tx] = (bf16)tile[tx][ty + 8*i];
}

// ---------------- grouped GEMM, 128x128 tile, 4 waves, 16x16x32 bf16 MFMA ----
// MODE 0: h = silu(x[gather] @ w1t^T + b1)   (K=1024, N=4096), h stored bf16
// MODE 1: out[token] += p * (h @ w2t^T + b2) (K=4096, N=1024), fp32 atomicAdd
template<int MODE>
__global__ __launch_bounds__(256) void moe_gemm(
    const float* __restrict__ X, const bf16* __restrict__ Ah,
    const bf16* __restrict__ Bt, const float* __restrict__ bias,
    bf16* __restrict__ Hout, float* __restrict__ Out,
    const int* __restrict__ token_ids, const float* __restrict__ pair_p,
    const int* __restrict__ slot_e, const int* __restrict__ slot_row0,
    const int* __restrict__ slot_gbase, const int* __restrict__ n_slots,
    const int* __restrict__ counts)
{
    constexpr int K = (MODE == 0) ? DMODEL : DFF;
    constexpr int N = (MODE == 0) ? DFF : DMODEL;

    int slot = blockIdx.x;
    if (slot >= *n_slots) return;
    int jt = blockIdx.y;
    int e = slot_e[slot], row0 = slot_row0[slot], gbase = slot_gbase[slot];
    int cnt = counts[e];

    __shared__ __align__(16) bf16 As[128 * LDSPITCH];
    __shared__ __align__(16) bf16 Bs[128 * LDSPITCH];

    int t = threadIdx.x;
    int r = t >> 1, half = t & 1;

    const float* aF = nullptr; const bf16* aB = nullptr;
    if (MODE == 0) {
        int tok = token_ids[gbase + row0 + r];
        aF = X + (size_t)tok * DMODEL + half * 16;
    } else {
        aB = Ah + (size_t)(gbase + row0 + r) * DFF + half * 16;
    }
    const bf16* bp = Bt + ((size_t)e * N + jt * 128 + r) * K + half * 16;

    int lane = t & 63, wv = t >> 6;
    int wm = (wv >> 1) * 64, wn = (wv & 1) * 64;
    int lr = lane & 15, kh = (lane >> 4) * 8;

    f32x4 acc[4][4] = {};

    bf16* aw = As + r * LDSPITCH + half * 16;
    bf16* bw = Bs + r * LDSPITCH + half * 16;

    for (int k0 = 0; k0 < K; k0 += 32) {
        __syncthreads();
        if (MODE == 0) {
            const float4* s4 = (const float4*)(aF + k0);
            float4 f0 = s4[0], f1 = s4[1], f2 = s4[2], f3 = s4[3];
            bf16x8 v0, v1;
            v0[0]=(bf16)f0.x; v0[1]=(bf16)f0.y; v0[2]=(bf16)f0.z; v0[3]=(bf16)f0.w;
            v0[4]=(bf16)f1.x; v0[5]=(bf16)f1.y; v0[6]=(bf16)f1.z; v0[7]=(bf16)f1.w;
            v1[0]=(bf16)f2.x; v1[1]=(bf16)f2.y; v1[2]=(bf16)f2.z; v1[3]=(bf16)f2.w;
            v1[4]=(bf16)f3.x; v1[5]=(bf16)f3.y; v1[6]=(bf16)f3.z; v1[7]=(bf16)f3.w;
            *(bf16x8*)aw = v0; *(bf16x8*)(aw + 8) = v1;
        } else {
            bf16x8 v0 = *(const bf16x8*)(aB + k0);
            bf16x8 v1 = *(const bf16x8*)(aB + k0 + 8);
            *(bf16x8*)aw = v0; *(bf16x8*)(aw + 8) = v1;
        }
        {
            bf16x8 w0 = *(const bf16x8*)(bp + k0);
            bf16x8 w1 = *(const bf16x8*)(bp + k0 + 8);
            *(bf16x8*)bw = w0; *(bf16x8*)(bw + 8) = w1;
        }
        __syncthreads();

        bf16x8 af[4], bfr[4];
        #pragma unroll
        for (int i = 0; i < 4; ++i)
            af[i] = *(const bf16x8*)(As + (wm + i*16 + lr) * LDSPITCH + kh);
        #pragma unroll
        for (int j = 0; j < 4; ++j)
            bfr[j] = *(const bf16x8*)(Bs + (wn + j*16 + lr) * LDSPITCH + kh);
        #pragma unroll
        for (int i = 0; i < 4; ++i)
            #pragma unroll
            for (int j = 0; j < 4; ++j)
                acc[i][j] = __builtin_amdgcn_mfma_f32_16x16x32_bf16(af[i], bfr[j], acc[i][j], 0, 0, 0);
    }

    int lro = (lane >> 4) * 4;
    if (MODE == 0) {
        #pragma unroll
        for (int i = 0; i < 4; ++i)
            #pragma unroll
            for (int reg = 0; reg < 4; ++reg) {
                int rl = wm + i*16 + lro + reg;
                size_t hrow = (size_t)(gbase + row0 + rl);
                #pragma unroll
                for (int j = 0; j < 4; ++j) {
                    int col = jt*128 + wn + j*16 + lr;
                    float v = acc[i][j][reg] + bias[e * DFF + col];
                    v = v / (1.0f + __expf(-v));       // silu
                    Hout[hrow * DFF + col] = (bf16)v;
                }
            }
    } else {
        #pragma unroll
        for (int i = 0; i < 4; ++i)
            #pragma unroll
            for (int reg = 0; reg < 4; ++reg) {
                int rl = wm + i*16 + lro + reg;
                if (row0 + rl < cnt) {
                    int pr = gbase + row0 + rl;
                    int tok = token_ids[pr];
                    float p = pair_p[pr];
                    #pragma unroll
                    for (int j = 0; j < 4; ++j) {
                        int col = jt*128 + wn + j*16 + lr;
                        float v = p * (acc[i][j][reg] + bias[e * DMODEL + col]);
                        atomicAdd(Out + (size_t)tok * DMODEL + col, v);
                    }
                }
            }
    }
}

// ---------------- launch ----------------
extern "C" void kernel_launch(void* const* d_in, const int* in_sizes, int n_in,
                              void* d_out, int out_size, void* d_ws, size_t ws_size,
                              hipStream_t stream)
{
    const float* x  = (const float*)d_in[0];
    const float* gw = (const float*)d_in[1];
    const float* gb = (const float*)d_in[2];
    const float* w1 = (const float*)d_in[3];
    const float* b1 = (const float*)d_in[4];
    const float* w2 = (const float*)d_in[5];
    const float* b2 = (const float*)d_in[6];
    float* out = (float*)d_out;

    const size_t W1T_OFF = 0;
    const size_t W2T_OFF = 67108864;            // 8*4096*1024*2
    const size_t H_OFF   = 134217728;
    const size_t RT_OFF  = H_OFF + (size_t)PAD_ROWS * DFF * 2;   // 276824064
    const size_t WS_NEEDED = RT_OFF + 272384;
    if (ws_size < WS_NEEDED) return;            // fail clean (poison stays -> absmax ~1.5)

    char* ws = (char*)d_ws;
    bf16* w1t = (bf16*)(ws + W1T_OFF);
    bf16* w2t = (bf16*)(ws + W2T_OFF);
    bf16* h   = (bf16*)(ws + H_OFF);
    char* rt  = ws + RT_OFF;
    int*   counts    = (int*)(rt + 0);
    int*   seg_base  = (int*)(rt + 32);
    int*   cursor    = (int*)(rt + 64);
    int*   n_slots   = (int*)(rt + 96);
    int*   slot_e    = (int*)(rt + 128);
    int*   slot_row0 = (int*)(rt + 768);
    int*   slot_gbase= (int*)(rt + 1408);
    int2*  topk_i    = (int2*)(rt + 2048);
    float2* topk_p   = (float2*)(rt + 67584);
    int*   token_ids = (int*)(rt + 133120);
    float* pair_p    = (float*)(rt + 202752);

    hipMemsetAsync(rt, 0, 128, stream);                         // counts/seg_base/cursor/n_slots
    hipMemsetAsync(token_ids, 0, PAD_ROWS * sizeof(int), stream);
    hipMemsetAsync(out, 0, (size_t)TOKENS * DMODEL * sizeof(float), stream);

    transpose_cvt<<<dim3(DFF/32, DMODEL/32, NEXP), dim3(32, 8), 0, stream>>>(w1, w1t, DMODEL, DFF);
    transpose_cvt<<<dim3(DMODEL/32, DFF/32, NEXP), dim3(32, 8), 0, stream>>>(w2, w2t, DFF, DMODEL);

    gate_kernel<<<TOKENS * 64 / 256, 256, 0, stream>>>(x, gw, gb, counts, topk_i, topk_p);
    build_slots<<<1, 64, 0, stream>>>(counts, seg_base, n_slots, slot_e, slot_row0, slot_gbase);
    scatter_kernel<<<TOKENS / 256, 256, 0, stream>>>(topk_i, topk_p, seg_base, cursor, token_ids, pair_p);

    moe_gemm<0><<<dim3(MAX_SLOTS, DFF/128), 256, 0, stream>>>(
        x, nullptr, w1t, b1, h, nullptr,
        token_ids, pair_p, slot_e, slot_row0, slot_gbase, n_slots, counts);
    moe_gemm<1><<<dim3(MAX_SLOTS, DMODEL/128), 256, 0, stream>>>(
        nullptr, h, w2t, b2, nullptr, out,
        token_ids, pair_p, slot_e, slot_row0, slot_gbase, n_slots, counts);
}

// Round 2
// 937.061 us; speedup vs baseline: 1.2217x; 1.2217x over previous
//
#include <hip/hip_runtime.h>
#include <hip/hip_bf16.h>
#include <math.h>

#define TOKENS 8192
#define DMODEL 1024
#define DFF    4096
#define NEXP   8
#define PAD_ROWS 17408     // 16384 + 8*128 worst-case padded pair rows
#define MAX_SLOTS 160      // worst case is 136 M-tiles
#define BK 64              // K-step per LDS stage

typedef __bf16 bf16;
typedef bf16  bf16x8 __attribute__((ext_vector_type(8)));
typedef float f32x4  __attribute__((ext_vector_type(4)));

// async global->LDS, 16B per lane. LDS dest is wave-uniform base + lane*16.
__device__ __forceinline__ void gload16(const bf16* g, bf16* l) {
    __builtin_amdgcn_global_load_lds(
        (const __attribute__((address_space(1))) void*)g,
        (__attribute__((address_space(3))) void*)l,
        16, 0, 0);
}

// ---------------- gating: one wave per token ----------------
__global__ __launch_bounds__(256) void gate_kernel(
    const float* __restrict__ x, const float* __restrict__ gw, const float* __restrict__ gb,
    int* __restrict__ counts, int2* __restrict__ topk_i, float2* __restrict__ topk_p)
{
    int wid  = (blockIdx.x * blockDim.x + threadIdx.x) >> 6;   // token id
    int lane = threadIdx.x & 63;
    if (wid >= TOKENS) return;
    const float* xr = x + (size_t)wid * DMODEL;
    float a0=0,a1=0,a2=0,a3=0,a4=0,a5=0,a6=0,a7=0;
    #pragma unroll
    for (int i = 0; i < DMODEL/64; ++i) {
        int d = lane + (i << 6);
        float xv = xr[d];
        const float4* g = (const float4*)(gw + (size_t)d * NEXP);
        float4 g0 = g[0], g1 = g[1];
        a0 += xv * g0.x; a1 += xv * g0.y; a2 += xv * g0.z; a3 += xv * g0.w;
        a4 += xv * g1.x; a5 += xv * g1.y; a6 += xv * g1.z; a7 += xv * g1.w;
    }
    #pragma unroll
    for (int off = 32; off; off >>= 1) {
        a0 += __shfl_xor(a0, off); a1 += __shfl_xor(a1, off);
        a2 += __shfl_xor(a2, off); a3 += __shfl_xor(a3, off);
        a4 += __shfl_xor(a4, off); a5 += __shfl_xor(a5, off);
        a6 += __shfl_xor(a6, off); a7 += __shfl_xor(a7, off);
    }
    float l[NEXP] = { a0+gb[0], a1+gb[1], a2+gb[2], a3+gb[3],
                      a4+gb[4], a5+gb[5], a6+gb[6], a7+gb[7] };
    float m = l[0];
    #pragma unroll
    for (int e = 1; e < NEXP; ++e) m = fmaxf(m, l[e]);
    float p[NEXP], s = 0.f;
    #pragma unroll
    for (int e = 0; e < NEXP; ++e) { p[e] = expf(l[e] - m); s += p[e]; }
    float inv = 1.0f / s;
    int i1 = 0; float b1v = p[0];
    #pragma unroll
    for (int e = 1; e < NEXP; ++e) if (p[e] > b1v) { b1v = p[e]; i1 = e; }
    int i2 = -1; float b2v = -1.f;
    #pragma unroll
    for (int e = 0; e < NEXP; ++e) if (e != i1 && p[e] > b2v) { b2v = p[e]; i2 = e; }
    if (lane == 0) {
        topk_i[wid] = make_int2(i1, i2);
        topk_p[wid] = make_float2(b1v * inv, b2v * inv);
        atomicAdd(&counts[i1], 1);
        atomicAdd(&counts[i2], 1);
    }
}

// ---------------- routing tables (trivial single-thread) ----------------
__global__ void build_slots(const int* __restrict__ counts, int* seg_base, int* n_slots,
                            int* slot_e, int* slot_row0, int* slot_gbase)
{
    if (threadIdx.x == 0 && blockIdx.x == 0) {
        int base = 0, s = 0;
        for (int e = 0; e < NEXP; ++e) {
            int c = counts[e];
            seg_base[e] = base;
            int nt = (c + 127) >> 7;
            for (int i = 0; i < nt; ++i) {
                slot_e[s] = e; slot_row0[s] = i << 7; slot_gbase[s] = base; ++s;
            }
            base += nt << 7;
        }
        *n_slots = s;
    }
}

__global__ __launch_bounds__(256) void scatter_kernel(
    const int2* __restrict__ topk_i, const float2* __restrict__ topk_p,
    const int* __restrict__ seg_base, int* __restrict__ cursor,
    int* __restrict__ token_ids, float* __restrict__ pair_p)
{
    int t = blockIdx.x * 256 + threadIdx.x;
    if (t >= TOKENS) return;
    int2 ki = topk_i[t]; float2 kp = topk_p[t];
    int p0 = seg_base[ki.x] + atomicAdd(&cursor[ki.x], 1);
    token_ids[p0] = t; pair_p[p0] = kp.x;
    int p1 = seg_base[ki.y] + atomicAdd(&cursor[ki.y], 1);
    token_ids[p1] = t; pair_p[p1] = kp.y;
}

// ---------------- fp32 [E][R][C] -> bf16 [E][C][R] ----------------
__global__ __launch_bounds__(256) void transpose_cvt(
    const float* __restrict__ src, bf16* __restrict__ dst, int R, int C)
{
    __shared__ float tile[32][33];
    int e = blockIdx.z;
    int c0 = blockIdx.x * 32, r0 = blockIdx.y * 32;
    const float* s = src + (size_t)e * R * C;
    bf16* d = dst + (size_t)e * R * C;
    int tx = threadIdx.x, ty = threadIdx.y;
    #pragma unroll
    for (int i = 0; i < 4; ++i)
        tile[ty + 8*i][tx] = s[(size_t)(r0 + ty + 8*i) * C + c0 + tx];
    __syncthreads();
    #pragma unroll
    for (int i = 0; i < 4; ++i)
        d[(size_t)(c0 + ty + 8*i) * R + r0 + tx] = (bf16)tile[tx][ty + 8*i];
}

// ---------------- x fp32 -> bf16 (for global_load_lds gather in GEMM1) -----
__global__ __launch_bounds__(256) void cvt_x(const float* __restrict__ x, bf16* __restrict__ xb)
{
    int i = blockIdx.x * 256 + threadIdx.x;      // 8 elems per thread
    const float4* s = (const float4*)x + (size_t)i * 2;
    float4 f0 = s[0], f1 = s[1];
    bf16x8 v;
    v[0]=(bf16)f0.x; v[1]=(bf16)f0.y; v[2]=(bf16)f0.z; v[3]=(bf16)f0.w;
    v[4]=(bf16)f1.x; v[5]=(bf16)f1.y; v[6]=(bf16)f1.z; v[7]=(bf16)f1.w;
    *((bf16x8*)xb + i) = v;
}

// ---------------- grouped GEMM, 128x128 tile, 4 waves, 16x16x32 bf16 MFMA ----
// MODE 0: h = silu(xb[gather] @ w1t^T + b1)   (K=1024, N=4096), h stored bf16
// MODE 1: out[token] += p * (h @ w2t^T + b2)  (K=4096, N=1024), fp32 atomicAdd
// Staging via global_load_lds(16B); LDS layout linear [128][BK] with XOR
// swizzle applied symmetrically: global source granule g = pos ^ (row&7),
// ds_read granule position = logical_granule ^ (row&7).
template<int MODE>
__global__ __launch_bounds__(256) void moe_gemm(
    const bf16* __restrict__ Xb, const bf16* __restrict__ Ah,
    const bf16* __restrict__ Bt, const float* __restrict__ bias,
    bf16* __restrict__ Hout, float* __restrict__ Out,
    const int* __restrict__ token_ids, const float* __restrict__ pair_p,
    const int* __restrict__ slot_e, const int* __restrict__ slot_row0,
    const int* __restrict__ slot_gbase, const int* __restrict__ n_slots,
    const int* __restrict__ counts)
{
    constexpr int K = (MODE == 0) ? DMODEL : DFF;
    constexpr int N = (MODE == 0) ? DFF : DMODEL;

    int slot = blockIdx.x;
    if (slot >= *n_slots) return;
    int jt = blockIdx.y;
    int e = slot_e[slot], row0 = slot_row0[slot], gbase = slot_gbase[slot];
    int cnt = counts[e];

    __shared__ __align__(16) bf16 As[128 * BK];   // 16 KB each
    __shared__ __align__(16) bf16 Bs[128 * BK];

    int t = threadIdx.x;
    int lane = t & 63, wv = t >> 6;

    // Wave wv stages rows [32wv, 32wv+32) of A and B: 4 instrs each, 8 rows/instr.
    // Lane l covers (row = base + l/8, granule_pos = l%8); source granule pre-swizzled.
    const bf16* aSrc[4]; const bf16* bSrc[4]; bf16* aDst[4]; bf16* bDst[4];
    #pragma unroll
    for (int i = 0; i < 4; ++i) {
        int row = 32*wv + i*8 + (lane >> 3);
        int g = (lane & 7) ^ (row & 7);
        if (MODE == 0) {
            int tok = token_ids[gbase + row0 + row];
            aSrc[i] = Xb + (size_t)tok * DMODEL + g*8;
        } else {
            aSrc[i] = Ah + (size_t)(gbase + row0 + row) * DFF + g*8;
        }
        bSrc[i] = Bt + ((size_t)e * N + jt*128 + row) * (size_t)K + g*8;
        aDst[i] = As + (32*wv + i*8) * BK;
        bDst[i] = Bs + (32*wv + i*8) * BK;
    }

    int wm = (wv >> 1) * 64, wn = (wv & 1) * 64;
    int lr = lane & 15, kq = lane >> 4;

    f32x4 acc[4][4] = {};

    for (int k0 = 0; k0 < K; k0 += BK) {
        __syncthreads();
        #pragma unroll
        for (int i = 0; i < 4; ++i) {
            gload16(aSrc[i] + k0, aDst[i]);
            gload16(bSrc[i] + k0, bDst[i]);
        }
        __syncthreads();   // compiler emits vmcnt(0) drain here (m97 structure)
        #pragma unroll
        for (int kk = 0; kk < 2; ++kk) {
            bf16x8 af[4], bg[4];
            #pragma unroll
            for (int i = 0; i < 4; ++i) {
                int row = wm + i*16 + lr;
                int gr = (kk*4 + kq) ^ (row & 7);
                af[i] = *(const bf16x8*)(As + row*BK + gr*8);
            }
            #pragma unroll
            for (int j = 0; j < 4; ++j) {
                int row = wn + j*16 + lr;
                int gr = (kk*4 + kq) ^ (row & 7);
                bg[j] = *(const bf16x8*)(Bs + row*BK + gr*8);
            }
            #pragma unroll
            for (int i = 0; i < 4; ++i)
                #pragma unroll
                for (int j = 0; j < 4; ++j)
                    acc[i][j] = __builtin_amdgcn_mfma_f32_16x16x32_bf16(af[i], bg[j], acc[i][j], 0, 0, 0);
        }
    }

    int lro = kq * 4;
    if (MODE == 0) {
        #pragma unroll
        for (int i = 0; i < 4; ++i)
            #pragma unroll
            for (int reg = 0; reg < 4; ++reg) {
                int rl = wm + i*16 + lro + reg;
                size_t hrow = (size_t)(gbase + row0 + rl);
                #pragma unroll
                for (int j = 0; j < 4; ++j) {
                    int col = jt*128 + wn + j*16 + lr;
                    float v = acc[i][j][reg] + bias[e * DFF + col];
                    v = v / (1.0f + __expf(-v));       // silu
                    Hout[hrow * DFF + col] = (bf16)v;
                }
            }
    } else {
        #pragma unroll
        for (int i = 0; i < 4; ++i)
            #pragma unroll
            for (int reg = 0; reg < 4; ++reg) {
                int rl = wm + i*16 + lro + reg;
                if (row0 + rl < cnt) {
                    int pr = gbase + row0 + rl;
                    int tok = token_ids[pr];
                    float p = pair_p[pr];
                    #pragma unroll
                    for (int j = 0; j < 4; ++j) {
                        int col = jt*128 + wn + j*16 + lr;
                        float v = p * (acc[i][j][reg] + bias[e * DMODEL + col]);
                        atomicAdd(Out + (size_t)tok * DMODEL + col, v);
                    }
                }
            }
    }
}

// ---------------- launch ----------------
extern "C" void kernel_launch(void* const* d_in, const int* in_sizes, int n_in,
                              void* d_out, int out_size, void* d_ws, size_t ws_size,
                              hipStream_t stream)
{
    const float* x  = (const float*)d_in[0];
    const float* gw = (const float*)d_in[1];
    const float* gb = (const float*)d_in[2];
    const float* w1 = (const float*)d_in[3];
    const float* b1 = (const float*)d_in[4];
    const float* w2 = (const float*)d_in[5];
    const float* b2 = (const float*)d_in[6];
    float* out = (float*)d_out;

    const size_t W1T_OFF = 0;
    const size_t W2T_OFF = 67108864;            // 8*4096*1024*2
    const size_t H_OFF   = 134217728;
    const size_t RT_OFF  = H_OFF + (size_t)PAD_ROWS * DFF * 2;   // 276824064
    const size_t WS_NEEDED = RT_OFF + 272384;
    if (ws_size < WS_NEEDED) return;            // fail clean

    char* ws = (char*)d_ws;
    bf16* w1t = (bf16*)(ws + W1T_OFF);
    bf16* w2t = (bf16*)(ws + W2T_OFF);
    bf16* xb  = (bf16*)(ws + W2T_OFF);          // aliases w2t: xb used only before w2 transpose
    bf16* h   = (bf16*)(ws + H_OFF);
    char* rt  = ws + RT_OFF;
    int*   counts    = (int*)(rt + 0);
    int*   seg_base  = (int*)(rt + 32);
    int*   cursor    = (int*)(rt + 64);
    int*   n_slots   = (int*)(rt + 96);
    int*   slot_e    = (int*)(rt + 128);
    int*   slot_row0 = (int*)(rt + 768);
    int*   slot_gbase= (int*)(rt + 1408);
    int2*  topk_i    = (int2*)(rt + 2048);
    float2* topk_p   = (float2*)(rt + 67584);
    int*   token_ids = (int*)(rt + 133120);
    float* pair_p    = (float*)(rt + 202752);

    hipMemsetAsync(rt, 0, 128, stream);                         // counts/seg_base/cursor/n_slots
    hipMemsetAsync(token_ids, 0, PAD_ROWS * sizeof(int), stream);
    hipMemsetAsync(out, 0, (size_t)TOKENS * DMODEL * sizeof(float), stream);

    transpose_cvt<<<dim3(DFF/32, DMODEL/32, NEXP), dim3(32, 8), 0, stream>>>(w1, w1t, DMODEL, DFF);
    cvt_x<<<TOKENS * DMODEL / 8 / 256, 256, 0, stream>>>(x, xb);

    gate_kernel<<<TOKENS * 64 / 256, 256, 0, stream>>>(x, gw, gb, counts, topk_i, topk_p);
    build_slots<<<1, 64, 0, stream>>>(counts, seg_base, n_slots, slot_e, slot_row0, slot_gbase);
    scatter_kernel<<<TOKENS / 256, 256, 0, stream>>>(topk_i, topk_p, seg_base, cursor, token_ids, pair_p);

    moe_gemm<0><<<dim3(MAX_SLOTS, DFF/128), 256, 0, stream>>>(
        xb, nullptr, w1t, b1, h, nullptr,
        token_ids, pair_p, slot_e, slot_row0, slot_gbase, n_slots, counts);

    // w2 transpose AFTER gemm1 so w2t can alias xb
    transpose_cvt<<<dim3(DMODEL/32, DFF/32, NEXP), dim3(32, 8), 0, stream>>>(w2, w2t, DFF, DMODEL);

    moe_gemm<1><<<dim3(MAX_SLOTS, DMODEL/128), 256, 0, stream>>>(
        nullptr, h, w2t, b2, nullptr, out,
        token_ids, pair_p, slot_e, slot_row0, slot_gbase, n_slots, counts);
}

// Round 3
// 932.119 us; speedup vs baseline: 1.2282x; 1.0053x over previous
//
#include <hip/hip_runtime.h>
#include <hip/hip_bf16.h>
#include <math.h>

#define TOKENS 8192
#define DMODEL 1024
#define DFF    4096
#define NEXP   8
#define PAD_ROWS 17408     // 16384 + 8*128 worst-case padded pair rows
#define MAX_SLOTS 160      // worst case is 136 M-tiles
#define BK 64              // K-step per LDS stage

typedef __bf16 bf16;
typedef bf16  bf16x8 __attribute__((ext_vector_type(8)));
typedef float f32x4  __attribute__((ext_vector_type(4)));

// async global->LDS, 16B per lane. LDS dest must be wave-uniform; HW adds lane*16.
__device__ __forceinline__ void gload16(const bf16* g, bf16* l) {
    __builtin_amdgcn_global_load_lds(
        (const __attribute__((address_space(1))) void*)g,
        (__attribute__((address_space(3))) void*)l,
        16, 0, 0);
}

// ---------------- gating: one wave per token (also emits xb = bf16(x)) -----
__global__ __launch_bounds__(256) void gate_kernel(
    const float* __restrict__ x, const float* __restrict__ gw, const float* __restrict__ gb,
    int* __restrict__ counts, int2* __restrict__ topk_i, float2* __restrict__ topk_p,
    bf16* __restrict__ xb)
{
    int wid  = (blockIdx.x * blockDim.x + threadIdx.x) >> 6;   // token id
    int lane = threadIdx.x & 63;
    if (wid >= TOKENS) return;
    const float* xr = x + (size_t)wid * DMODEL;
    bf16* xbr = xb + (size_t)wid * DMODEL;
    float a0=0,a1=0,a2=0,a3=0,a4=0,a5=0,a6=0,a7=0;
    #pragma unroll
    for (int i = 0; i < DMODEL/64; ++i) {
        int d = lane + (i << 6);
        float xv = xr[d];
        xbr[d] = (bf16)xv;                       // fused x -> bf16 (128B/wave stores)
        const float4* g = (const float4*)(gw + (size_t)d * NEXP);
        float4 g0 = g[0], g1 = g[1];
        a0 += xv * g0.x; a1 += xv * g0.y; a2 += xv * g0.z; a3 += xv * g0.w;
        a4 += xv * g1.x; a5 += xv * g1.y; a6 += xv * g1.z; a7 += xv * g1.w;
    }
    #pragma unroll
    for (int off = 32; off; off >>= 1) {
        a0 += __shfl_xor(a0, off); a1 += __shfl_xor(a1, off);
        a2 += __shfl_xor(a2, off); a3 += __shfl_xor(a3, off);
        a4 += __shfl_xor(a4, off); a5 += __shfl_xor(a5, off);
        a6 += __shfl_xor(a6, off); a7 += __shfl_xor(a7, off);
    }
    float l[NEXP] = { a0+gb[0], a1+gb[1], a2+gb[2], a3+gb[3],
                      a4+gb[4], a5+gb[5], a6+gb[6], a7+gb[7] };
    float m = l[0];
    #pragma unroll
    for (int e = 1; e < NEXP; ++e) m = fmaxf(m, l[e]);
    float p[NEXP], s = 0.f;
    #pragma unroll
    for (int e = 0; e < NEXP; ++e) { p[e] = expf(l[e] - m); s += p[e]; }
    float inv = 1.0f / s;
    int i1 = 0; float b1v = p[0];
    #pragma unroll
    for (int e = 1; e < NEXP; ++e) if (p[e] > b1v) { b1v = p[e]; i1 = e; }
    int i2 = -1; float b2v = -1.f;
    #pragma unroll
    for (int e = 0; e < NEXP; ++e) if (e != i1 && p[e] > b2v) { b2v = p[e]; i2 = e; }
    if (lane == 0) {
        topk_i[wid] = make_int2(i1, i2);
        topk_p[wid] = make_float2(b1v * inv, b2v * inv);
        atomicAdd(&counts[i1], 1);
        atomicAdd(&counts[i2], 1);
    }
}

// ---------------- routing tables (trivial single-thread) ----------------
__global__ void build_slots(const int* __restrict__ counts, int* seg_base, int* n_slots,
                            int* slot_e, int* slot_row0, int* slot_gbase)
{
    if (threadIdx.x == 0 && blockIdx.x == 0) {
        int base = 0, s = 0;
        for (int e = 0; e < NEXP; ++e) {
            int c = counts[e];
            seg_base[e] = base;
            int nt = (c + 127) >> 7;
            for (int i = 0; i < nt; ++i) {
                slot_e[s] = e; slot_row0[s] = i << 7; slot_gbase[s] = base; ++s;
            }
            base += nt << 7;
        }
        *n_slots = s;
    }
}

__global__ __launch_bounds__(256) void scatter_kernel(
    const int2* __restrict__ topk_i, const float2* __restrict__ topk_p,
    const int* __restrict__ seg_base, int* __restrict__ cursor,
    int* __restrict__ token_ids, float* __restrict__ pair_p)
{
    int t = blockIdx.x * 256 + threadIdx.x;
    if (t >= TOKENS) return;
    int2 ki = topk_i[t]; float2 kp = topk_p[t];
    int p0 = seg_base[ki.x] + atomicAdd(&cursor[ki.x], 1);
    token_ids[p0] = t; pair_p[p0] = kp.x;
    int p1 = seg_base[ki.y] + atomicAdd(&cursor[ki.y], 1);
    token_ids[p1] = t; pair_p[p1] = kp.y;
}

// ---------------- fp32 [E][R][C] -> bf16 [E][C][R], 64x64 tiles ------------
__global__ __launch_bounds__(256) void transpose_cvt(
    const float* __restrict__ src, bf16* __restrict__ dst, int R, int C)
{
    __shared__ float tile[64][65];
    int e = blockIdx.z;
    int c0 = blockIdx.x * 64, r0 = blockIdx.y * 64;
    const float* s = src + (size_t)e * R * C;
    bf16* d = dst + (size_t)e * R * C;
    int tx = threadIdx.x, ty = threadIdx.y;     // 64, 4
    #pragma unroll
    for (int k = 0; k < 16; ++k)
        tile[ty + 4*k][tx] = s[(size_t)(r0 + ty + 4*k) * C + c0 + tx];   // 256B/wave
    __syncthreads();
    #pragma unroll
    for (int k = 0; k < 16; ++k)
        d[(size_t)(c0 + ty + 4*k) * R + r0 + tx] = (bf16)tile[tx][ty + 4*k];  // 128B/wave
}

// ---------------- grouped GEMM, 128x128 tile, 4 waves, counted-vmcnt dbuf ---
// MODE 0: h = silu(xb[gather] @ w1t^T + b1)   (K=1024, N=4096), h stored bf16
// MODE 1: out[token] += p * (h @ w2t^T + b2)  (K=4096, N=1024), fp32 atomicAdd
// Pipeline: issue tile t+1's 8 global_load_lds, s_waitcnt vmcnt(8) (tile t
// landed, t+1 stays in flight under the 32 MFMAs), raw s_barrier pair.
template<int MODE>
__global__ __launch_bounds__(256, 2) void moe_gemm(
    const bf16* __restrict__ Xb, const bf16* __restrict__ Ah,
    const bf16* __restrict__ Bt, const float* __restrict__ bias,
    bf16* __restrict__ Hout, float* __restrict__ Out,
    const int* __restrict__ token_ids, const float* __restrict__ pair_p,
    const int* __restrict__ slot_e, const int* __restrict__ slot_row0,
    const int* __restrict__ slot_gbase, const int* __restrict__ n_slots,
    const int* __restrict__ counts)
{
    constexpr int K = (MODE == 0) ? DMODEL : DFF;
    constexpr int N = (MODE == 0) ? DFF : DMODEL;
    constexpr int NJT = N / 128;
    constexpr int NT = K / BK;

    // XCD-bijective swizzle (slot-major linear id): same-slot blocks -> same XCD L2
    int nwg = gridDim.x;                        // multiple of 8 by construction
    int bid = blockIdx.x;
    int wid = (bid & 7) * (nwg >> 3) + (bid >> 3);
    int slot = wid / NJT, jt = wid % NJT;
    if (slot >= *n_slots) return;

    int e = slot_e[slot], row0 = slot_row0[slot], gbase = slot_gbase[slot];
    int cnt = counts[e];

    __shared__ __align__(16) bf16 As[2][128 * BK];   // 16 KB each buffer
    __shared__ __align__(16) bf16 Bs[2][128 * BK];

    int t = threadIdx.x;
    int lane = t & 63, wv = t >> 6;

    // Wave wv stages rows [32wv, 32wv+32): 4 instrs/operand, 8 rows/instr.
    // Lane l -> (row = base + l/8, LDS granule = l%8), source granule = (l%8)^(row&7).
    const bf16* aSrc[4]; const bf16* bSrc[4];
    #pragma unroll
    for (int i = 0; i < 4; ++i) {
        int row = 32*wv + i*8 + (lane >> 3);
        int g = (lane & 7) ^ (row & 7);
        if (MODE == 0) {
            int tok = token_ids[gbase + row0 + row];
            aSrc[i] = Xb + (size_t)tok * DMODEL + g*8;
        } else {
            aSrc[i] = Ah + (size_t)(gbase + row0 + row) * DFF + g*8;
        }
        bSrc[i] = Bt + ((size_t)e * N + jt*128 + row) * (size_t)K + g*8;
    }

    int wm = (wv >> 1) * 64, wn = (wv & 1) * 64;
    int lr = lane & 15, kq = lane >> 4;

    f32x4 acc[4][4] = {};

    // prologue: issue tile 0 into buffer 0
    #pragma unroll
    for (int i = 0; i < 4; ++i) {
        gload16(aSrc[i], &As[0][(32*wv + i*8) * BK]);
        gload16(bSrc[i], &Bs[0][(32*wv + i*8) * BK]);
    }

    for (int tt = 0; tt < NT; ++tt) {
        int cur = tt & 1, nxt = cur ^ 1;
        int k1 = (tt + 1 < NT) ? (tt + 1) * BK : 0;   // last iter: junk re-read of tile 0
        #pragma unroll
        for (int i = 0; i < 4; ++i) {
            gload16(aSrc[i] + k1, &As[nxt][(32*wv + i*8) * BK]);
            gload16(bSrc[i] + k1, &Bs[nxt][(32*wv + i*8) * BK]);
        }
        // wait tile tt (oldest 8) landed; tile tt+1's 8 stay in flight
        asm volatile("s_waitcnt vmcnt(8)" ::: "memory");
        __builtin_amdgcn_s_barrier();
        asm volatile("" ::: "memory");

        const bf16* As_c = &As[cur][0];
        const bf16* Bs_c = &Bs[cur][0];
        #pragma unroll
        for (int kk = 0; kk < 2; ++kk) {
            bf16x8 af[4], bg[4];
            #pragma unroll
            for (int i = 0; i < 4; ++i) {
                int row = wm + i*16 + lr;
                int gr = (kk*4 + kq) ^ (row & 7);
                af[i] = *(const bf16x8*)(As_c + row*BK + gr*8);
            }
            #pragma unroll
            for (int j = 0; j < 4; ++j) {
                int row = wn + j*16 + lr;
                int gr = (kk*4 + kq) ^ (row & 7);
                bg[j] = *(const bf16x8*)(Bs_c + row*BK + gr*8);
            }
            #pragma unroll
            for (int i = 0; i < 4; ++i)
                #pragma unroll
                for (int j = 0; j < 4; ++j)
                    acc[i][j] = __builtin_amdgcn_mfma_f32_16x16x32_bf16(af[i], bg[j], acc[i][j], 0, 0, 0);
        }
        asm volatile("" ::: "memory");
        __builtin_amdgcn_s_barrier();   // all waves done reading cur before next iter overwrites it
    }

    int lro = kq * 4;
    if (MODE == 0) {
        #pragma unroll
        for (int i = 0; i < 4; ++i)
            #pragma unroll
            for (int reg = 0; reg < 4; ++reg) {
                int rl = wm + i*16 + lro + reg;
                size_t hrow = (size_t)(gbase + row0 + rl);
                #pragma unroll
                for (int j = 0; j < 4; ++j) {
                    int col = jt*128 + wn + j*16 + lr;
                    float v = acc[i][j][reg] + bias[e * DFF + col];
                    v = v / (1.0f + __expf(-v));       // silu
                    Hout[hrow * DFF + col] = (bf16)v;
                }
            }
    } else {
        #pragma unroll
        for (int i = 0; i < 4; ++i)
            #pragma unroll
            for (int reg = 0; reg < 4; ++reg) {
                int rl = wm + i*16 + lro + reg;
                if (row0 + rl < cnt) {
                    int pr = gbase + row0 + rl;
                    int tok = token_ids[pr];
                    float p = pair_p[pr];
                    #pragma unroll
                    for (int j = 0; j < 4; ++j) {
                        int col = jt*128 + wn + j*16 + lr;
                        float v = p * (acc[i][j][reg] + bias[e * DMODEL + col]);
                        atomicAdd(Out + (size_t)tok * DMODEL + col, v);
                    }
                }
            }
    }
}

// ---------------- launch ----------------
extern "C" void kernel_launch(void* const* d_in, const int* in_sizes, int n_in,
                              void* d_out, int out_size, void* d_ws, size_t ws_size,
                              hipStream_t stream)
{
    const float* x  = (const float*)d_in[0];
    const float* gw = (const float*)d_in[1];
    const float* gb = (const float*)d_in[2];
    const float* w1 = (const float*)d_in[3];
    const float* b1 = (const float*)d_in[4];
    const float* w2 = (const float*)d_in[5];
    const float* b2 = (const float*)d_in[6];
    float* out = (float*)d_out;

    const size_t W1T_OFF = 0;
    const size_t W2T_OFF = 67108864;            // 8*4096*1024*2
    const size_t H_OFF   = 134217728;
    const size_t RT_OFF  = H_OFF + (size_t)PAD_ROWS * DFF * 2;   // 276824064
    const size_t WS_NEEDED = RT_OFF + 272384;
    if (ws_size < WS_NEEDED) return;            // fail clean

    char* ws = (char*)d_ws;
    bf16* w1t = (bf16*)(ws + W1T_OFF);
    bf16* w2t = (bf16*)(ws + W2T_OFF);
    bf16* xb  = (bf16*)(ws + W2T_OFF);          // aliases w2t: xb used only before w2 transpose
    bf16* h   = (bf16*)(ws + H_OFF);
    char* rt  = ws + RT_OFF;
    int*   counts    = (int*)(rt + 0);
    int*   seg_base  = (int*)(rt + 32);
    int*   cursor    = (int*)(rt + 64);
    int*   n_slots   = (int*)(rt + 96);
    int*   slot_e    = (int*)(rt + 128);
    int*   slot_row0 = (int*)(rt + 768);
    int*   slot_gbase= (int*)(rt + 1408);
    int2*  topk_i    = (int2*)(rt + 2048);
    float2* topk_p   = (float2*)(rt + 67584);
    int*   token_ids = (int*)(rt + 133120);
    float* pair_p    = (float*)(rt + 202752);

    hipMemsetAsync(rt, 0, 128, stream);                         // counts/seg_base/cursor/n_slots
    hipMemsetAsync(token_ids, 0, PAD_ROWS * sizeof(int), stream);
    hipMemsetAsync(out, 0, (size_t)TOKENS * DMODEL * sizeof(float), stream);

    transpose_cvt<<<dim3(DFF/64, DMODEL/64, NEXP), dim3(64, 4), 0, stream>>>(w1, w1t, DMODEL, DFF);

    gate_kernel<<<TOKENS * 64 / 256, 256, 0, stream>>>(x, gw, gb, counts, topk_i, topk_p, xb);
    build_slots<<<1, 64, 0, stream>>>(counts, seg_base, n_slots, slot_e, slot_row0, slot_gbase);
    scatter_kernel<<<TOKENS / 256, 256, 0, stream>>>(topk_i, topk_p, seg_base, cursor, token_ids, pair_p);

    moe_gemm<0><<<MAX_SLOTS * (DFF/128), 256, 0, stream>>>(
        xb, nullptr, w1t, b1, h, nullptr,
        token_ids, pair_p, slot_e, slot_row0, slot_gbase, n_slots, counts);

    // w2 transpose AFTER gemm1 so w2t can alias xb
    transpose_cvt<<<dim3(DMODEL/64, DFF/64, NEXP), dim3(64, 4), 0, stream>>>(w2, w2t, DFF, DMODEL);

    moe_gemm<1><<<MAX_SLOTS * (DMODEL/128), 256, 0, stream>>>(
        nullptr, h, w2t, b2, nullptr, out,
        token_ids, pair_p, slot_e, slot_row0, slot_gbase, n_slots, counts);
}